// Round 3
// baseline (1141.051 us; speedup 1.0000x reference)
//
#include <hip/hip_runtime.h>

typedef __bf16 bf16_t;
typedef bf16_t bf16x8 __attribute__((ext_vector_type(8)));
typedef float  f32x4  __attribute__((ext_vector_type(4)));

constexpr int Bb  = 4;
constexpr int Din = 256;
constexpr int Ss  = 2048;
constexpr int Dm  = 512;
constexpr int Hh  = 8;
constexpr int Dk  = 64;
constexpr int NHd = 32;     // B*H
constexpr float LOG2E = 1.44269504088896340736f;

#define MFMA16(a, b, c) __builtin_amdgcn_mfma_f32_16x16x32_bf16((a), (b), (c), 0, 0, 0)

__device__ __forceinline__ void fsplit(float x, bf16_t& h, bf16_t& l) {
    bf16_t hh = (bf16_t)x;
    h = hh;
    l = (bf16_t)(x - (float)hh);
}
__device__ __forceinline__ bf16x8 ldfrag(const bf16_t* p) {
    return *reinterpret_cast<const bf16x8*>(p);
}

// ---------------------------------------------------------------------------
// prep_x: x [B][DIN][S] fp32 -> xt hi/lo [B][S][DIN] bf16 (transpose + split)
// ---------------------------------------------------------------------------
__global__ void prep_x(const float* __restrict__ x, bf16_t* __restrict__ xh,
                       bf16_t* __restrict__ xl) {
    __shared__ float t[32][33];
    int b = blockIdx.z, i0 = blockIdx.y * 32, s0 = blockIdx.x * 32;
    int tx = threadIdx.x, ty = threadIdx.y;  // 32 x 8
    const float* xb = x + ((size_t)b * Din + i0) * Ss + s0;
#pragma unroll
    for (int r = 0; r < 4; ++r) t[ty + r * 8][tx] = xb[(size_t)(ty + r * 8) * Ss + tx];
    __syncthreads();
#pragma unroll
    for (int r = 0; r < 4; ++r) {
        int srow = ty + r * 8;
        float v = t[tx][srow];
        size_t o = ((size_t)b * Ss + s0 + srow) * Din + i0 + tx;
        bf16_t h, l;
        fsplit(v, h, l);
        xh[o] = h;
        xl[o] = l;
    }
}

// ---------------------------------------------------------------------------
// prep_w: split Wq/Wk into bf16 hi/lo, cast Wv/Wo to bf16 hi. All are 512*256.
// ---------------------------------------------------------------------------
__global__ void prep_w(const float* __restrict__ Wq, const float* __restrict__ Wk,
                       const float* __restrict__ Wv, const float* __restrict__ Wo,
                       bf16_t* wqh, bf16_t* wql, bf16_t* wkh, bf16_t* wkl,
                       bf16_t* wvh, bf16_t* woh) {
    int e = blockIdx.x * 256 + threadIdx.x;  // grid covers exactly 512*256
    bf16_t h, l;
    fsplit(Wq[e], h, l); wqh[e] = h; wql[e] = l;
    fsplit(Wk[e], h, l); wkh[e] = h; wkl[e] = l;
    wvh[e] = (bf16_t)Wv[e];
    woh[e] = (bf16_t)Wo[e];
}

// ---------------------------------------------------------------------------
// proj_qkv: fused Q/K/V projection. blockIdx.y encodes (which, b):
//   which 0: Q = xt @ Wq^T + bq  (split-bf16, hi/lo out, head layout)
//   which 1: K = xt @ Wk^T + bk  (split-bf16, hi/lo out, head layout)
//   which 2: Vt = Wv @ xt^T + bv (plain bf16, [n][d][s] layout)
// launch_bounds(256,4): 128-VGPR budget (grid is 3 blocks/CU; 4-block class).
// ---------------------------------------------------------------------------
__global__ __launch_bounds__(256, 4)
void proj_qkv(const bf16_t* __restrict__ xh, const bf16_t* __restrict__ xl,
              const bf16_t* __restrict__ wqh, const bf16_t* __restrict__ wql,
              const bf16_t* __restrict__ wkh, const bf16_t* __restrict__ wkl,
              const bf16_t* __restrict__ wvh,
              const float* __restrict__ bq, const float* __restrict__ bk,
              const float* __restrict__ bv,
              bf16_t* __restrict__ Qhi, bf16_t* __restrict__ Qlo,
              bf16_t* __restrict__ Khi, bf16_t* __restrict__ Klo,
              bf16_t* __restrict__ Vt) {
    int z = blockIdx.y;
    int b = z & 3, which = z >> 2;  // 0=Q, 1=K, 2=V (block-uniform branch)
    int mt = blockIdx.x & 7, sb = blockIdx.x >> 3;
    int wave = threadIdx.x >> 6, lane = threadIdx.x & 63;
    int l15 = lane & 15, quad = lane >> 4;

    if (which < 2) {
        const bf16_t* wh = which ? wkh : wqh;
        const bf16_t* wl = which ? wkl : wql;
        const float* bias = which ? bk : bq;
        bf16_t* outh = which ? Khi : Qhi;
        bf16_t* outl = which ? Klo : Qlo;
        int s0 = sb * 256 + wave * 64, m0 = mt * 64;
        const bf16_t* xhb = xh + ((size_t)b * Ss + s0 + l15) * Din + quad * 8;
        const bf16_t* xlb = xl + ((size_t)b * Ss + s0 + l15) * Din + quad * 8;
        const bf16_t* whb = wh + (size_t)(m0 + l15) * Din + quad * 8;
        const bf16_t* wlb = wl + (size_t)(m0 + l15) * Din + quad * 8;
        f32x4 acc[4][4] = {};  // [s-tile][m-tile]
        for (int ks = 0; ks < 8; ++ks) {
            bf16x8 ah[4], al[4], bh[4], bl[4];
#pragma unroll
            for (int st = 0; st < 4; ++st) {
                ah[st] = ldfrag(xhb + (size_t)st * 16 * Din + ks * 32);
                al[st] = ldfrag(xlb + (size_t)st * 16 * Din + ks * 32);
            }
#pragma unroll
            for (int nt = 0; nt < 4; ++nt) {
                bh[nt] = ldfrag(whb + (size_t)nt * 16 * Din + ks * 32);
                bl[nt] = ldfrag(wlb + (size_t)nt * 16 * Din + ks * 32);
            }
#pragma unroll
            for (int st = 0; st < 4; ++st)
#pragma unroll
                for (int nt = 0; nt < 4; ++nt) {
                    acc[st][nt] = MFMA16(ah[st], bh[nt], acc[st][nt]);
                    acc[st][nt] = MFMA16(ah[st], bl[nt], acc[st][nt]);
                    acc[st][nt] = MFMA16(al[st], bh[nt], acc[st][nt]);
                }
        }
        int h = m0 >> 6;  // head within this b
#pragma unroll
        for (int nt = 0; nt < 4; ++nt) {
            int m = m0 + nt * 16 + l15;
            float bb = bias[m];
            int d = m & 63;
#pragma unroll
            for (int st = 0; st < 4; ++st)
#pragma unroll
                for (int r = 0; r < 4; ++r) {
                    int s = s0 + st * 16 + quad * 4 + r;
                    float v = acc[st][nt][r] + bb;
                    bf16_t hh, ll;
                    fsplit(v, hh, ll);
                    size_t o = ((size_t)(b * Hh + h) * Ss + s) * Dk + d;
                    outh[o] = hh;
                    outl[o] = ll;
                }
        }
    } else {
        int m0 = mt * 64, s0 = sb * 256 + wave * 64;
        const bf16_t* ab = wvh + (size_t)(m0 + l15) * Din + quad * 8;
        const bf16_t* bb = xh + ((size_t)b * Ss + s0 + l15) * Din + quad * 8;
        f32x4 acc[4][4] = {};  // [m-tile][s-tile]
        for (int ks = 0; ks < 8; ++ks) {
            bf16x8 af[4], bf_[4];
#pragma unroll
            for (int i = 0; i < 4; ++i) {
                af[i] = ldfrag(ab + (size_t)i * 16 * Din + ks * 32);
                bf_[i] = ldfrag(bb + (size_t)i * 16 * Din + ks * 32);
            }
#pragma unroll
            for (int i = 0; i < 4; ++i)
#pragma unroll
                for (int j = 0; j < 4; ++j) acc[i][j] = MFMA16(af[i], bf_[j], acc[i][j]);
        }
#pragma unroll
        for (int i = 0; i < 4; ++i)
#pragma unroll
            for (int r = 0; r < 4; ++r) {
                int m = m0 + i * 16 + quad * 4 + r;
                float bvv = bv[m];
#pragma unroll
                for (int j = 0; j < 4; ++j) {
                    int s = s0 + j * 16 + l15;
                    Vt[((size_t)b * Dm + m) * Ss + s] = (bf16_t)(acc[i][j][r] + bvv);
                }
            }
    }
}

// ---------------------------------------------------------------------------
// attn_kernel: per (head, 64-q tile). Wave owns 16 q-rows, sweeps all 2048 keys.
// XCD head-grouping keeps per-XCD K/V set at 3MB (L2-resident; r2: FETCH -8x).
// launch_bounds(256,4): 128 VGPR so 8-fragment K batches stay in registers.
// attw stores staged through fp32 LDS -> one 256B contiguous NT store per row.
// ---------------------------------------------------------------------------
__global__ __launch_bounds__(256, 4)
void attn_kernel(const bf16_t* __restrict__ Qhi, const bf16_t* __restrict__ Qlo,
                 const bf16_t* __restrict__ Khi, const bf16_t* __restrict__ Klo,
                 const bf16_t* __restrict__ Vt, bf16_t* __restrict__ AO,
                 float* __restrict__ attw) {
    __shared__ __align__(16) bf16_t pbuf[4][16][72];   // bf16 P for PV MFMA
    __shared__ __align__(16) float  wbuf[4][16][76];   // fp32 w staging (stride 76: bank-clean)
    int bid = blockIdx.y * 32 + blockIdx.x;  // grid is (32, 32)
    int xcd = bid & 7, idx = bid >> 3;       // dispatch maps bid%8 -> XCD
    int head = xcd * 4 + (idx >> 5);         // 4 heads per XCD
    int qt = idx & 31;
    int wave = threadIdx.x >> 6, lane = threadIdx.x & 63;
    int l15 = lane & 15, quad = lane >> 4;
    int q0 = qt * 64 + wave * 16;

    const bf16_t* qh_p = Qhi + ((size_t)head * Ss + q0 + l15) * Dk + quad * 8;
    const bf16_t* ql_p = Qlo + ((size_t)head * Ss + q0 + l15) * Dk + quad * 8;
    bf16x8 qah[2], qal[2];
#pragma unroll
    for (int ks = 0; ks < 2; ++ks) {
        qah[ks] = ldfrag(qh_p + ks * 32);
        qal[ks] = ldfrag(ql_p + ks * 32);
    }
    const bf16_t* kh_b = Khi + (size_t)head * Ss * Dk;
    const bf16_t* kl_b = Klo + (size_t)head * Ss * Dk;
    const bf16_t* v_b  = Vt + (size_t)head * Dk * Ss;

    // ---- pass 1: row sums of exp(s) (no max trick: |s| <~ 16, fp32-safe) ----
    float lsum[4] = {0.f, 0.f, 0.f, 0.f};
    for (int kc = 0; kc < Ss; kc += 64) {
#pragma unroll
        for (int np = 0; np < 2; ++np) {
            bf16x8 kh[2][2], kl[2][2];
#pragma unroll
            for (int i = 0; i < 2; ++i) {
                int nt = np * 2 + i;
                const bf16_t* kp = kh_b + (size_t)(kc + nt * 16 + l15) * Dk + quad * 8;
                const bf16_t* lp = kl_b + (size_t)(kc + nt * 16 + l15) * Dk + quad * 8;
#pragma unroll
                for (int ks = 0; ks < 2; ++ks) {
                    kh[i][ks] = ldfrag(kp + ks * 32);
                    kl[i][ks] = ldfrag(lp + ks * 32);
                }
            }
#pragma unroll
            for (int i = 0; i < 2; ++i) {
                f32x4 sc = {0.f, 0.f, 0.f, 0.f};
#pragma unroll
                for (int ks = 0; ks < 2; ++ks) {
                    sc = MFMA16(qah[ks], kh[i][ks], sc);
                    sc = MFMA16(qah[ks], kl[i][ks], sc);
                    sc = MFMA16(qal[ks], kh[i][ks], sc);
                }
#pragma unroll
                for (int r = 0; r < 4; ++r) lsum[r] += __builtin_amdgcn_exp2f(sc[r] * LOG2E);
            }
        }
    }
#pragma unroll
    for (int r = 0; r < 4; ++r) {  // merge across the 16 column-lanes
        float v = lsum[r];
        v += __shfl_xor(v, 1);
        v += __shfl_xor(v, 2);
        v += __shfl_xor(v, 4);
        v += __shfl_xor(v, 8);
        lsum[r] = v;
    }
    float linv[4];
#pragma unroll
    for (int r = 0; r < 4; ++r) linv[r] = 1.0f / lsum[r];

    // ---- pass 2 ----
    f32x4 oacc[4] = {};  // [d-tile] C[16q][16d]
    float* aw_base = attw + ((size_t)head * Ss + q0) * Ss;
    for (int kc = 0; kc < Ss; kc += 64) {
#pragma unroll
        for (int np = 0; np < 2; ++np) {
            bf16x8 kh[2][2], kl[2][2];
#pragma unroll
            for (int i = 0; i < 2; ++i) {
                int nt = np * 2 + i;
                const bf16_t* kp = kh_b + (size_t)(kc + nt * 16 + l15) * Dk + quad * 8;
                const bf16_t* lp = kl_b + (size_t)(kc + nt * 16 + l15) * Dk + quad * 8;
#pragma unroll
                for (int ks = 0; ks < 2; ++ks) {
                    kh[i][ks] = ldfrag(kp + ks * 32);
                    kl[i][ks] = ldfrag(lp + ks * 32);
                }
            }
#pragma unroll
            for (int i = 0; i < 2; ++i) {
                int nt = np * 2 + i;
                f32x4 sc = {0.f, 0.f, 0.f, 0.f};
#pragma unroll
                for (int ks = 0; ks < 2; ++ks) {
                    sc = MFMA16(qah[ks], kh[i][ks], sc);
                    sc = MFMA16(qah[ks], kl[i][ks], sc);
                    sc = MFMA16(qal[ks], kh[i][ks], sc);
                }
#pragma unroll
                for (int r = 0; r < 4; ++r) {
                    float w = __builtin_amdgcn_exp2f(sc[r] * LOG2E) * linv[r];
                    int q = quad * 4 + r;
                    wbuf[wave][q][nt * 16 + l15] = w;
                    pbuf[wave][q][nt * 16 + l15] = (bf16_t)w;
                }
            }
        }
        // V loads land while the row stores drain
        bf16x8 vb[2][4];
#pragma unroll
        for (int ks = 0; ks < 2; ++ks)
#pragma unroll
            for (int dt = 0; dt < 4; ++dt)
                vb[ks][dt] = ldfrag(v_b + (size_t)(dt * 16 + l15) * Ss + kc + ks * 32 + quad * 8);
        // coalesced attw stores: one 256B contiguous NT store per q-row
#pragma unroll
        for (int q = 0; q < 16; ++q) {
            float wv = wbuf[wave][q][lane];
            __builtin_nontemporal_store(wv, &aw_base[(size_t)q * Ss + kc + lane]);
        }
        // P @ V over this 64-key chunk (pbuf is wave-private; lgkmcnt handles RAW)
#pragma unroll
        for (int ks = 0; ks < 2; ++ks) {
            bf16x8 pa = *reinterpret_cast<const bf16x8*>(&pbuf[wave][l15][ks * 32 + quad * 8]);
#pragma unroll
            for (int dt = 0; dt < 4; ++dt) oacc[dt] = MFMA16(pa, vb[ks][dt], oacc[dt]);
        }
    }
    // store AO: flat [s'][n][d] bf16 (torch-faithful flat layout)
#pragma unroll
    for (int dt = 0; dt < 4; ++dt)
#pragma unroll
        for (int r = 0; r < 4; ++r) {
            int q = q0 + quad * 4 + r;
            int col = head * Dk + dt * 16 + l15;
            AO[(size_t)q * (NHd * Dk) + col] = (bf16_t)oacc[dt][r];
        }
}

// ---------------------------------------------------------------------------
// out_kernel: Z[b][i][s] = sum_e Wo[i][e] * AO_scrambled[b][s][e] + bo[i]
// AO row base for (b,s): (b*512 + s/4)*2048 + (s%4)*512  (contiguous in e!)
// Grid (64,2,4)=512 blocks -> 2 blocks/CU, wave tile 32i x 32s.
// ---------------------------------------------------------------------------
__global__ __launch_bounds__(256, 4)
void out_kernel(const bf16_t* __restrict__ AO, const bf16_t* __restrict__ woh,
                const float* __restrict__ bo, float* __restrict__ Z) {
    int b = blockIdx.z, it = blockIdx.y, sb = blockIdx.x;  // grid (64, 2, 4)
    int wave = threadIdx.x >> 6, lane = threadIdx.x & 63;
    int l15 = lane & 15, quad = lane >> 4;
    int i0 = it * 128 + wave * 32, s0 = sb * 32;
    const bf16_t* wop = woh + (size_t)(i0 + l15) * Dm + quad * 8;
    size_t bbase[2];
#pragma unroll
    for (int nt = 0; nt < 2; ++nt) {
        int s = s0 + nt * 16 + l15;
        bbase[nt] = ((size_t)(b * 512 + (s >> 2)) * 2048) + (size_t)(s & 3) * 512 + quad * 8;
    }
    f32x4 acc[2][2] = {};  // [i-tile][s-tile]
    for (int ks = 0; ks < 16; ++ks) {
        bf16x8 af[2], bf_[2];
#pragma unroll
        for (int mt = 0; mt < 2; ++mt) af[mt] = ldfrag(wop + (size_t)mt * 16 * Dm + ks * 32);
#pragma unroll
        for (int nt = 0; nt < 2; ++nt) bf_[nt] = ldfrag(AO + bbase[nt] + ks * 32);
#pragma unroll
        for (int mt = 0; mt < 2; ++mt)
#pragma unroll
            for (int nt = 0; nt < 2; ++nt) acc[mt][nt] = MFMA16(af[mt], bf_[nt], acc[mt][nt]);
    }
#pragma unroll
    for (int mt = 0; mt < 2; ++mt)
#pragma unroll
        for (int r = 0; r < 4; ++r) {
            int i = i0 + mt * 16 + quad * 4 + r;
            float bias = bo[i];
#pragma unroll
            for (int nt = 0; nt < 2; ++nt) {
                int s = s0 + nt * 16 + l15;
                __builtin_nontemporal_store(acc[mt][nt][r] + bias,
                                            &Z[((size_t)b * Din + i) * Ss + s]);
            }
        }
}

// ---------------------------------------------------------------------------
extern "C" void kernel_launch(void* const* d_in, const int* in_sizes, int n_in,
                              void* d_out, int out_size, void* d_ws, size_t ws_size,
                              hipStream_t stream) {
    const float* x  = (const float*)d_in[0];
    const float* Wq = (const float*)d_in[1];
    const float* bq = (const float*)d_in[2];
    const float* Wk = (const float*)d_in[3];
    const float* bk = (const float*)d_in[4];
    const float* Wv = (const float*)d_in[5];
    const float* bv = (const float*)d_in[6];
    const float* Wo = (const float*)d_in[7];
    const float* bo = (const float*)d_in[8];

    float* Z    = (float*)d_out;
    float* attw = Z + (size_t)Bb * Din * Ss;  // 2,097,152 floats in

    char* ws = (char*)d_ws;
    constexpr size_t SZ_XT = (size_t)Bb * Ss * Din * 2;   // 4 MB
    constexpr size_t SZ_W  = (size_t)Dm * Din * 2;        // 256 KB
    constexpr size_t SZ_Q  = (size_t)NHd * Ss * Dk * 2;   // 8 MB
    bf16_t* xh  = (bf16_t*)(ws);
    bf16_t* xl  = (bf16_t*)(ws + SZ_XT);
    bf16_t* wqh = (bf16_t*)(ws + 2 * SZ_XT);
    bf16_t* wql = (bf16_t*)(ws + 2 * SZ_XT + SZ_W);
    bf16_t* wkh = (bf16_t*)(ws + 2 * SZ_XT + 2 * SZ_W);
    bf16_t* wkl = (bf16_t*)(ws + 2 * SZ_XT + 3 * SZ_W);
    bf16_t* wvh = (bf16_t*)(ws + 2 * SZ_XT + 4 * SZ_W);
    bf16_t* woh = (bf16_t*)(ws + 2 * SZ_XT + 5 * SZ_W);
    char* p2 = ws + 2 * SZ_XT + 6 * SZ_W;
    bf16_t* Qhi = (bf16_t*)(p2);
    bf16_t* Qlo = (bf16_t*)(p2 + SZ_Q);
    bf16_t* Khi = (bf16_t*)(p2 + 2 * SZ_Q);
    bf16_t* Klo = (bf16_t*)(p2 + 3 * SZ_Q);
    bf16_t* Vt  = (bf16_t*)(p2 + 4 * SZ_Q);
    bf16_t* AO  = (bf16_t*)(p2 + 5 * SZ_Q);

    prep_x<<<dim3(Ss / 32, Din / 32, Bb), dim3(32, 8), 0, stream>>>(x, xh, xl);
    prep_w<<<dim3((Dm * Din) / 256), dim3(256), 0, stream>>>(Wq, Wk, Wv, Wo, wqh, wql, wkh,
                                                             wkl, wvh, woh);
    proj_qkv<<<dim3(64, 12), dim3(256), 0, stream>>>(xh, xl, wqh, wql, wkh, wkl, wvh,
                                                     bq, bk, bv, Qhi, Qlo, Khi, Klo, Vt);
    attn_kernel<<<dim3(32, 32), dim3(256), 0, stream>>>(Qhi, Qlo, Khi, Klo, Vt, AO, attw);
    out_kernel<<<dim3(64, 2, 4), dim3(256), 0, stream>>>(AO, woh, bo, Z);
}

// Round 5
// 762.502 us; speedup vs baseline: 1.4965x; 1.4965x over previous
//
#include <hip/hip_runtime.h>

typedef __bf16 bf16_t;
typedef bf16_t bf16x8 __attribute__((ext_vector_type(8)));
typedef float  f32x4  __attribute__((ext_vector_type(4)));

constexpr int Bb  = 4;
constexpr int Din = 256;
constexpr int Ss  = 2048;
constexpr int Dm  = 512;
constexpr int Hh  = 8;
constexpr int Dk  = 64;
constexpr int NHd = 32;     // B*H
constexpr float LOG2E = 1.44269504088896340736f;

#define MFMA16(a, b, c) __builtin_amdgcn_mfma_f32_16x16x32_bf16((a), (b), (c), 0, 0, 0)

// async global->LDS DMA, 16B per lane. dest = ldsbase + lane*16 (linear);
// src is per-lane. Swizzled LDS content is achieved by pre-swizzling src (T21).
typedef __attribute__((address_space(1))) const unsigned int ga_u32;
typedef __attribute__((address_space(3))) unsigned int ls_u32;
#define GLOAD_LDS16(gsrc, ldst)                                                   \
    __builtin_amdgcn_global_load_lds((ga_u32*)(gsrc), (ls_u32*)(ldst), 16, 0, 0)

__device__ __forceinline__ void fsplit(float x, bf16_t& h, bf16_t& l) {
    bf16_t hh = (bf16_t)x;
    h = hh;
    l = (bf16_t)(x - (float)hh);
}
__device__ __forceinline__ bf16x8 ldfrag(const bf16_t* p) {
    return *reinterpret_cast<const bf16x8*>(p);
}

// ---------------------------------------------------------------------------
// prep_x: x [B][DIN][S] fp32 -> xt hi/lo [B][S][DIN] bf16 (transpose + split)
// ---------------------------------------------------------------------------
__global__ void prep_x(const float* __restrict__ x, bf16_t* __restrict__ xh,
                       bf16_t* __restrict__ xl) {
    __shared__ float t[32][33];
    int b = blockIdx.z, i0 = blockIdx.y * 32, s0 = blockIdx.x * 32;
    int tx = threadIdx.x, ty = threadIdx.y;  // 32 x 8
    const float* xb = x + ((size_t)b * Din + i0) * Ss + s0;
#pragma unroll
    for (int r = 0; r < 4; ++r) t[ty + r * 8][tx] = xb[(size_t)(ty + r * 8) * Ss + tx];
    __syncthreads();
#pragma unroll
    for (int r = 0; r < 4; ++r) {
        int srow = ty + r * 8;
        float v = t[tx][srow];
        size_t o = ((size_t)b * Ss + s0 + srow) * Din + i0 + tx;
        bf16_t h, l;
        fsplit(v, h, l);
        xh[o] = h;
        xl[o] = l;
    }
}

// ---------------------------------------------------------------------------
// prep_w: split Wq/Wk into bf16 hi/lo, cast Wv/Wo to bf16 hi. All are 512*256.
// ---------------------------------------------------------------------------
__global__ void prep_w(const float* __restrict__ Wq, const float* __restrict__ Wk,
                       const float* __restrict__ Wv, const float* __restrict__ Wo,
                       bf16_t* wqh, bf16_t* wql, bf16_t* wkh, bf16_t* wkl,
                       bf16_t* wvh, bf16_t* woh) {
    int e = blockIdx.x * 256 + threadIdx.x;  // grid covers exactly 512*256
    bf16_t h, l;
    fsplit(Wq[e], h, l); wqh[e] = h; wql[e] = l;
    fsplit(Wk[e], h, l); wkh[e] = h; wkl[e] = l;
    wvh[e] = (bf16_t)Wv[e];
    woh[e] = (bf16_t)Wo[e];
}

// ---------------------------------------------------------------------------
// proj_qkv: fused Q/K/V projection. blockIdx.y encodes (which, b):
//   which 0: Q = xt @ Wq^T + bq  (split-bf16, hi/lo out, head layout)
//   which 1: K = xt @ Wk^T + bk  (split-bf16, hi/lo out, head layout)
//   which 2: Vt = Wv @ xt^T + bv (plain bf16, [n][d][s] layout)
// ---------------------------------------------------------------------------
__global__ __launch_bounds__(256, 4)
void proj_qkv(const bf16_t* __restrict__ xh, const bf16_t* __restrict__ xl,
              const bf16_t* __restrict__ wqh, const bf16_t* __restrict__ wql,
              const bf16_t* __restrict__ wkh, const bf16_t* __restrict__ wkl,
              const bf16_t* __restrict__ wvh,
              const float* __restrict__ bq, const float* __restrict__ bk,
              const float* __restrict__ bv,
              bf16_t* __restrict__ Qhi, bf16_t* __restrict__ Qlo,
              bf16_t* __restrict__ Khi, bf16_t* __restrict__ Klo,
              bf16_t* __restrict__ Vt) {
    int z = blockIdx.y;
    int b = z & 3, which = z >> 2;  // 0=Q, 1=K, 2=V (block-uniform branch)
    int mt = blockIdx.x & 7, sb = blockIdx.x >> 3;
    int wave = threadIdx.x >> 6, lane = threadIdx.x & 63;
    int l15 = lane & 15, quad = lane >> 4;

    if (which < 2) {
        const bf16_t* wh = which ? wkh : wqh;
        const bf16_t* wl = which ? wkl : wql;
        const float* bias = which ? bk : bq;
        bf16_t* outh = which ? Khi : Qhi;
        bf16_t* outl = which ? Klo : Qlo;
        int s0 = sb * 256 + wave * 64, m0 = mt * 64;
        const bf16_t* xhb = xh + ((size_t)b * Ss + s0 + l15) * Din + quad * 8;
        const bf16_t* xlb = xl + ((size_t)b * Ss + s0 + l15) * Din + quad * 8;
        const bf16_t* whb = wh + (size_t)(m0 + l15) * Din + quad * 8;
        const bf16_t* wlb = wl + (size_t)(m0 + l15) * Din + quad * 8;
        f32x4 acc[4][4] = {};  // [s-tile][m-tile]
        for (int ks = 0; ks < 8; ++ks) {
            bf16x8 ah[4], al[4], bh[4], bl[4];
#pragma unroll
            for (int st = 0; st < 4; ++st) {
                ah[st] = ldfrag(xhb + (size_t)st * 16 * Din + ks * 32);
                al[st] = ldfrag(xlb + (size_t)st * 16 * Din + ks * 32);
            }
#pragma unroll
            for (int nt = 0; nt < 4; ++nt) {
                bh[nt] = ldfrag(whb + (size_t)nt * 16 * Din + ks * 32);
                bl[nt] = ldfrag(wlb + (size_t)nt * 16 * Din + ks * 32);
            }
#pragma unroll
            for (int st = 0; st < 4; ++st)
#pragma unroll
                for (int nt = 0; nt < 4; ++nt) {
                    acc[st][nt] = MFMA16(ah[st], bh[nt], acc[st][nt]);
                    acc[st][nt] = MFMA16(ah[st], bl[nt], acc[st][nt]);
                    acc[st][nt] = MFMA16(al[st], bh[nt], acc[st][nt]);
                }
        }
        int h = m0 >> 6;  // head within this b
#pragma unroll
        for (int nt = 0; nt < 4; ++nt) {
            int m = m0 + nt * 16 + l15;
            float bb = bias[m];
            int d = m & 63;
#pragma unroll
            for (int st = 0; st < 4; ++st)
#pragma unroll
                for (int r = 0; r < 4; ++r) {
                    int s = s0 + st * 16 + quad * 4 + r;
                    float v = acc[st][nt][r] + bb;
                    bf16_t hh, ll;
                    fsplit(v, hh, ll);
                    size_t o = ((size_t)(b * Hh + h) * Ss + s) * Dk + d;
                    outh[o] = hh;
                    outl[o] = ll;
                }
        }
    } else {
        int m0 = mt * 64, s0 = sb * 256 + wave * 64;
        const bf16_t* ab = wvh + (size_t)(m0 + l15) * Din + quad * 8;
        const bf16_t* bb = xh + ((size_t)b * Ss + s0 + l15) * Din + quad * 8;
        f32x4 acc[4][4] = {};  // [m-tile][s-tile]
        for (int ks = 0; ks < 8; ++ks) {
            bf16x8 af[4], bf_[4];
#pragma unroll
            for (int i = 0; i < 4; ++i) {
                af[i] = ldfrag(ab + (size_t)i * 16 * Din + ks * 32);
                bf_[i] = ldfrag(bb + (size_t)i * 16 * Din + ks * 32);
            }
#pragma unroll
            for (int i = 0; i < 4; ++i)
#pragma unroll
                for (int j = 0; j < 4; ++j) acc[i][j] = MFMA16(af[i], bf_[j], acc[i][j]);
        }
#pragma unroll
        for (int i = 0; i < 4; ++i)
#pragma unroll
            for (int r = 0; r < 4; ++r) {
                int m = m0 + i * 16 + quad * 4 + r;
                float bvv = bv[m];
#pragma unroll
                for (int j = 0; j < 4; ++j) {
                    int s = s0 + j * 16 + l15;
                    Vt[((size_t)b * Dm + m) * Ss + s] = (bf16_t)(acc[i][j][r] + bvv);
                }
            }
    }
}

// ---------------------------------------------------------------------------
// attn_kernel: per (head, 64-q tile). Wave owns 16 q-rows, sweeps all 2048 keys.
// K-hi/K-lo/V chunks staged in LDS via global_load_lds DMA, shared by all 4
// waves (4x fewer loads, latency paid once per chunk). Row-major [64][128B]
// LDS tiles XOR-swizzled (byte ^= (row&7)<<4) via pre-swizzled global src (T21)
// to avoid the 16-way ds_read_b128 bank conflict. LDS 33.8KB -> 4 blocks/CU.
// ---------------------------------------------------------------------------
__global__ __launch_bounds__(256, 4)
void attn_kernel(const bf16_t* __restrict__ Qhi, const bf16_t* __restrict__ Qlo,
                 const bf16_t* __restrict__ Khi, const bf16_t* __restrict__ Klo,
                 const bf16_t* __restrict__ Vt, bf16_t* __restrict__ AO,
                 float* __restrict__ attw) {
    __shared__ __align__(16) bf16_t kbh[64 * 64];      // 8KB K-hi chunk, swizzled
    __shared__ __align__(16) bf16_t kbl[64 * 64];      // 8KB K-lo chunk, swizzled
    __shared__ __align__(16) bf16_t vbf[64 * 64];      // 8KB V chunk [d][key], swizzled
    __shared__ __align__(16) bf16_t pbuf[4][16][72];   // bf16 P for PV MFMA (wave-private)

    int bid = blockIdx.y * 32 + blockIdx.x;  // grid is (32, 32)
    int xcd = bid & 7, idx = bid >> 3;       // dispatch maps bid%8 -> XCD
    int head = xcd * 4 + (idx >> 5);         // 4 heads per XCD
    int qt = idx & 31;
    int wave = threadIdx.x >> 6, lane = threadIdx.x & 63;
    int l15 = lane & 15, quad = lane >> 4;
    int q0 = qt * 64 + wave * 16;

    const bf16_t* qh_p = Qhi + ((size_t)head * Ss + q0 + l15) * Dk + quad * 8;
    const bf16_t* ql_p = Qlo + ((size_t)head * Ss + q0 + l15) * Dk + quad * 8;
    bf16x8 qah[2], qal[2];
#pragma unroll
    for (int ks = 0; ks < 2; ++ks) {
        qah[ks] = ldfrag(qh_p + ks * 32);
        qal[ks] = ldfrag(ql_p + ks * 32);
    }
    const bf16_t* kh_b = Khi + (size_t)head * Ss * Dk;
    const bf16_t* kl_b = Klo + (size_t)head * Ss * Dk;
    const bf16_t* v_b  = Vt + (size_t)head * Dk * Ss;

    // --- staging offsets. Each wave DMAs LDS bytes [wave*2048, wave*2048+2048)
    // of each 8KB buffer via 2 instructions (1KB each, lane*16 linear dest).
    // Content at LDS byte L must be global byte (L ^ swz(row)), row = L>>7.
    int Lb0 = wave * 2048 + lane * 16;
    int koffe[2];   // element offset within a K chunk (contiguous 8KB)
    size_t voffe[2];  // element offset within V rows (row stride Ss)
#pragma unroll
    for (int j = 0; j < 2; ++j) {
        int L = Lb0 + j * 1024;
        int row = L >> 7;
        int sw = (row & 7) << 4;
        koffe[j] = (L ^ sw) >> 1;
        voffe[j] = (size_t)row * Ss + (((L & 127) ^ sw) >> 1);
    }
    int ldsoff = (wave * 2048) >> 1;  // element offset of this wave's LDS segment

    // ---- pass 1: row sums of exp(s) (no max trick: |s| <~ 16, fp32-safe) ----
    float lsum[4] = {0.f, 0.f, 0.f, 0.f};
    for (int kc = 0; kc < Ss; kc += 64) {
        const bf16_t* kh_c = kh_b + (size_t)kc * Dk;
        const bf16_t* kl_c = kl_b + (size_t)kc * Dk;
#pragma unroll
        for (int j = 0; j < 2; ++j) {
            GLOAD_LDS16(kh_c + koffe[j], &kbh[ldsoff + j * 512]);
            GLOAD_LDS16(kl_c + koffe[j], &kbl[ldsoff + j * 512]);
        }
        __syncthreads();  // drains DMA (vmcnt) + aligns waves
#pragma unroll
        for (int nt = 0; nt < 4; ++nt) {
            int krow = nt * 16 + l15;
            int cb = (krow & 7) << 4;
            const char* khp = (const char*)kbh + krow * 128;
            const char* klp = (const char*)kbl + krow * 128;
            f32x4 sc = {0.f, 0.f, 0.f, 0.f};
#pragma unroll
            for (int ks = 0; ks < 2; ++ks) {
                bf16x8 kbhv = *(const bf16x8*)(khp + ((ks * 64 + quad * 16) ^ cb));
                bf16x8 kblv = *(const bf16x8*)(klp + ((ks * 64 + quad * 16) ^ cb));
                sc = MFMA16(qah[ks], kbhv, sc);
                sc = MFMA16(qah[ks], kblv, sc);
                sc = MFMA16(qal[ks], kbhv, sc);
            }
#pragma unroll
            for (int r = 0; r < 4; ++r) lsum[r] += __builtin_amdgcn_exp2f(sc[r] * LOG2E);
        }
        __syncthreads();  // all reads done before next chunk's DMA overwrites
    }
#pragma unroll
    for (int r = 0; r < 4; ++r) {  // merge across the 16 column-lanes
        float v = lsum[r];
        v += __shfl_xor(v, 1);
        v += __shfl_xor(v, 2);
        v += __shfl_xor(v, 4);
        v += __shfl_xor(v, 8);
        lsum[r] = v;
    }
    float linv[4];
#pragma unroll
    for (int r = 0; r < 4; ++r) linv[r] = 1.0f / lsum[r];

    // ---- pass 2 ----
    f32x4 oacc[4] = {};  // [d-tile] C[16q][16d]
    float* aw_base = attw + ((size_t)head * Ss + q0) * Ss;
    for (int kc = 0; kc < Ss; kc += 64) {
        const bf16_t* kh_c = kh_b + (size_t)kc * Dk;
        const bf16_t* kl_c = kl_b + (size_t)kc * Dk;
        const bf16_t* v_c  = v_b + kc;
#pragma unroll
        for (int j = 0; j < 2; ++j) {
            GLOAD_LDS16(kh_c + koffe[j], &kbh[ldsoff + j * 512]);
            GLOAD_LDS16(kl_c + koffe[j], &kbl[ldsoff + j * 512]);
            GLOAD_LDS16(v_c + voffe[j], &vbf[ldsoff + j * 512]);
        }
        __syncthreads();
#pragma unroll
        for (int nt = 0; nt < 4; ++nt) {
            int krow = nt * 16 + l15;
            int cb = (krow & 7) << 4;
            const char* khp = (const char*)kbh + krow * 128;
            const char* klp = (const char*)kbl + krow * 128;
            f32x4 sc = {0.f, 0.f, 0.f, 0.f};
#pragma unroll
            for (int ks = 0; ks < 2; ++ks) {
                bf16x8 kbhv = *(const bf16x8*)(khp + ((ks * 64 + quad * 16) ^ cb));
                bf16x8 kblv = *(const bf16x8*)(klp + ((ks * 64 + quad * 16) ^ cb));
                sc = MFMA16(qah[ks], kbhv, sc);
                sc = MFMA16(qah[ks], kblv, sc);
                sc = MFMA16(qal[ks], kbhv, sc);
            }
            int k0 = kc + nt * 16;
#pragma unroll
            for (int r = 0; r < 4; ++r) {
                float w = __builtin_amdgcn_exp2f(sc[r] * LOG2E) * linv[r];
                int q = quad * 4 + r;
                __builtin_nontemporal_store(w, &aw_base[(size_t)q * Ss + k0 + l15]);
                pbuf[wave][q][nt * 16 + l15] = (bf16_t)w;
            }
        }
        // P @ V over this 64-key chunk (pbuf wave-private; lgkmcnt handles RAW)
#pragma unroll
        for (int ks = 0; ks < 2; ++ks) {
            bf16x8 pa = *reinterpret_cast<const bf16x8*>(&pbuf[wave][l15][ks * 32 + quad * 8]);
#pragma unroll
            for (int dt = 0; dt < 4; ++dt) {
                int vrow = dt * 16 + l15;
                int vb_sw = (vrow & 7) << 4;
                bf16x8 vbv = *(const bf16x8*)((const char*)vbf + vrow * 128 +
                                              ((ks * 64 + quad * 16) ^ vb_sw));
                oacc[dt] = MFMA16(pa, vbv, oacc[dt]);
            }
        }
        __syncthreads();
    }
    // store AO: flat [s'][n][d] bf16 (torch-faithful flat layout)
#pragma unroll
    for (int dt = 0; dt < 4; ++dt)
#pragma unroll
        for (int r = 0; r < 4; ++r) {
            int q = q0 + quad * 4 + r;
            int col = head * Dk + dt * 16 + l15;
            AO[(size_t)q * (NHd * Dk) + col] = (bf16_t)oacc[dt][r];
        }
}

// ---------------------------------------------------------------------------
// out_kernel: Z[b][i][s] = sum_e Wo[i][e] * AO_scrambled[b][s][e] + bo[i]
// AO row base for (b,s): (b*512 + s/4)*2048 + (s%4)*512  (contiguous in e!)
// ---------------------------------------------------------------------------
__global__ __launch_bounds__(256, 4)
void out_kernel(const bf16_t* __restrict__ AO, const bf16_t* __restrict__ woh,
                const float* __restrict__ bo, float* __restrict__ Z) {
    int b = blockIdx.z, it = blockIdx.y, sb = blockIdx.x;  // grid (64, 2, 4)
    int wave = threadIdx.x >> 6, lane = threadIdx.x & 63;
    int l15 = lane & 15, quad = lane >> 4;
    int i0 = it * 128 + wave * 32, s0 = sb * 32;
    const bf16_t* wop = woh + (size_t)(i0 + l15) * Dm + quad * 8;
    size_t bbase[2];
#pragma unroll
    for (int nt = 0; nt < 2; ++nt) {
        int s = s0 + nt * 16 + l15;
        bbase[nt] = ((size_t)(b * 512 + (s >> 2)) * 2048) + (size_t)(s & 3) * 512 + quad * 8;
    }
    f32x4 acc[2][2] = {};  // [i-tile][s-tile]
    for (int ks = 0; ks < 16; ++ks) {
        bf16x8 af[2], bf_[2];
#pragma unroll
        for (int mt = 0; mt < 2; ++mt) af[mt] = ldfrag(wop + (size_t)mt * 16 * Dm + ks * 32);
#pragma unroll
        for (int nt = 0; nt < 2; ++nt) bf_[nt] = ldfrag(AO + bbase[nt] + ks * 32);
#pragma unroll
        for (int mt = 0; mt < 2; ++mt)
#pragma unroll
            for (int nt = 0; nt < 2; ++nt) acc[mt][nt] = MFMA16(af[mt], bf_[nt], acc[mt][nt]);
    }
#pragma unroll
    for (int mt = 0; mt < 2; ++mt)
#pragma unroll
        for (int r = 0; r < 4; ++r) {
            int i = i0 + mt * 16 + quad * 4 + r;
            float bias = bo[i];
#pragma unroll
            for (int nt = 0; nt < 2; ++nt) {
                int s = s0 + nt * 16 + l15;
                __builtin_nontemporal_store(acc[mt][nt][r] + bias,
                                            &Z[((size_t)b * Din + i) * Ss + s]);
            }
        }
}

// ---------------------------------------------------------------------------
extern "C" void kernel_launch(void* const* d_in, const int* in_sizes, int n_in,
                              void* d_out, int out_size, void* d_ws, size_t ws_size,
                              hipStream_t stream) {
    const float* x  = (const float*)d_in[0];
    const float* Wq = (const float*)d_in[1];
    const float* bq = (const float*)d_in[2];
    const float* Wk = (const float*)d_in[3];
    const float* bk = (const float*)d_in[4];
    const float* Wv = (const float*)d_in[5];
    const float* bv = (const float*)d_in[6];
    const float* Wo = (const float*)d_in[7];
    const float* bo = (const float*)d_in[8];

    float* Z    = (float*)d_out;
    float* attw = Z + (size_t)Bb * Din * Ss;  // 2,097,152 floats in

    char* ws = (char*)d_ws;
    constexpr size_t SZ_XT = (size_t)Bb * Ss * Din * 2;   // 4 MB
    constexpr size_t SZ_W  = (size_t)Dm * Din * 2;        // 256 KB
    constexpr size_t SZ_Q  = (size_t)NHd * Ss * Dk * 2;   // 8 MB
    bf16_t* xh  = (bf16_t*)(ws);
    bf16_t* xl  = (bf16_t*)(ws + SZ_XT);
    bf16_t* wqh = (bf16_t*)(ws + 2 * SZ_XT);
    bf16_t* wql = (bf16_t*)(ws + 2 * SZ_XT + SZ_W);
    bf16_t* wkh = (bf16_t*)(ws + 2 * SZ_XT + 2 * SZ_W);
    bf16_t* wkl = (bf16_t*)(ws + 2 * SZ_XT + 3 * SZ_W);
    bf16_t* wvh = (bf16_t*)(ws + 2 * SZ_XT + 4 * SZ_W);
    bf16_t* woh = (bf16_t*)(ws + 2 * SZ_XT + 5 * SZ_W);
    char* p2 = ws + 2 * SZ_XT + 6 * SZ_W;
    bf16_t* Qhi = (bf16_t*)(p2);
    bf16_t* Qlo = (bf16_t*)(p2 + SZ_Q);
    bf16_t* Khi = (bf16_t*)(p2 + 2 * SZ_Q);
    bf16_t* Klo = (bf16_t*)(p2 + 3 * SZ_Q);
    bf16_t* Vt  = (bf16_t*)(p2 + 4 * SZ_Q);
    bf16_t* AO  = (bf16_t*)(p2 + 5 * SZ_Q);

    prep_x<<<dim3(Ss / 32, Din / 32, Bb), dim3(32, 8), 0, stream>>>(x, xh, xl);
    prep_w<<<dim3((Dm * Din) / 256), dim3(256), 0, stream>>>(Wq, Wk, Wv, Wo, wqh, wql, wkh,
                                                             wkl, wvh, woh);
    proj_qkv<<<dim3(64, 12), dim3(256), 0, stream>>>(xh, xl, wqh, wql, wkh, wkl, wvh,
                                                     bq, bk, bv, Qhi, Qlo, Khi, Klo, Vt);
    attn_kernel<<<dim3(32, 32), dim3(256), 0, stream>>>(Qhi, Qlo, Khi, Klo, Vt, AO, attw);
    out_kernel<<<dim3(64, 2, 4), dim3(256), 0, stream>>>(AO, woh, bo, Z);
}